// Round 8
// baseline (129.853 us; speedup 1.0000x reference)
//
#include <hip/hip_runtime.h>
#include <stdint.h>
#include <math.h>

// Fused softmax + top-8 (renormalized) over 64 experts.
// Fast kernel: 1 wave = 8 tokens; 8 lanes/token; 8 logits/lane.
//   Value-only u32 network (v_max_u32/v_min_u32, full rate, no vcc),
//   exact index recovery via rank-binsearch + byte-OR delivery.
//   Ties (dup value among qualifiers) are DETECTED exactly and flagged to
//   d_ws (1 bit per token, 1 byte per wave); outputs for flagged tokens are
//   provisional.
// Fixup kernel: scans flags, exactly redoes flagged tokens (scalar, stable
//   tie-break = lowest expert index, matching jax.lax.top_k).
// Fallback (ws too small): R4's exact f64 max/min network kernel.

typedef float f32x4 __attribute__((ext_vector_type(4)));

#define DPP_QUAD_XOR1   0xB1   // quad_perm(1,0,3,2)  : lane ^ 1
#define DPP_QUAD_XOR2   0x4E   // quad_perm(2,3,0,1)  : lane ^ 2
#define DPP_HALF_MIRROR 0x141  // row_half_mirror     : lane <-> 7-lane (in 8)

template<int CTRL>
static __device__ __forceinline__ uint32_t dpp32(uint32_t x) {
    return (uint32_t)__builtin_amdgcn_update_dpp(0, (int)x, CTRL, 0xF, 0xF, true);
}
template<int CTRL>
static __device__ __forceinline__ uint64_t dpp64(uint64_t x) {
    int lo = __builtin_amdgcn_update_dpp(0, (int)(uint32_t)x,         CTRL, 0xF, 0xF, true);
    int hi = __builtin_amdgcn_update_dpp(0, (int)(uint32_t)(x >> 32), CTRL, 0xF, 0xF, true);
    return ((uint64_t)(uint32_t)hi << 32) | (uint32_t)lo;
}
template<int CTRL>
static __device__ __forceinline__ float dppf(float x) {
    int i = __builtin_amdgcn_update_dpp(0, __float_as_int(x), CTRL, 0xF, 0xF, true);
    return __int_as_float(i);
}

// compare-exchange desc on u32: v_max_u32 + v_min_u32 (no vcc dependency)
#define CE32(x, y) { uint32_t gt_ = (x > y) ? x : y; uint32_t lt_ = (x > y) ? y : x; \
                     x = gt_; y = lt_; }

template<int CTRL>
static __device__ __forceinline__ void merge_u32(uint32_t k[8]) {
    uint32_t m[8];
#pragma unroll
    for (int i = 0; i < 8; ++i) {
        uint32_t p = dpp32<CTRL>(k[7 - i]);
        m[i] = (k[i] > p) ? k[i] : p;
    }
    CE32(m[0], m[4]) CE32(m[1], m[5]) CE32(m[2], m[6]) CE32(m[3], m[7])
    CE32(m[0], m[2]) CE32(m[1], m[3]) CE32(m[4], m[6]) CE32(m[5], m[7])
    CE32(m[0], m[1]) CE32(m[2], m[3]) CE32(m[4], m[5]) CE32(m[6], m[7])
#pragma unroll
    for (int i = 0; i < 8; ++i) k[i] = m[i];
}

static __device__ __forceinline__ uint32_t mono(float v) {
    uint32_t u = __float_as_uint(v);
    return u ^ (uint32_t)(((int32_t)u >> 31) | 0x80000000);   // ascending map
}
static __device__ __forceinline__ float unmono(uint32_t m) {
    uint32_t u = (m & 0x80000000u) ? (m ^ 0x80000000u) : ~m;
    return __uint_as_float(u);
}

__global__ __launch_bounds__(256) void topk_fast(
    const float* __restrict__ logits,
    float* __restrict__ out_w,
    float* __restrict__ out_id,
    float* __restrict__ out_tei,
    unsigned char* __restrict__ flags,
    int T)
{
    const int  lane = threadIdx.x & 63;
    const int  wv   = (int)(threadIdx.x >> 6);
    const long t0   = (long)blockIdx.x * 32 + (long)wv * 8;   // first token of wave
    if (t0 >= T) return;

    const int  sub = lane & 7;
    const bool act = (t0 + (lane >> 3)) < T;

    const f32x4* src = reinterpret_cast<const f32x4*>(logits)
                     + (act ? (t0 * 16 + (long)lane * 2) : 0);
    f32x4 a = __builtin_nontemporal_load(src);
    f32x4 b = __builtin_nontemporal_load(src + 1);

    // originals (ascending-mapped); expert id of o[j] is sub*8 + j
    uint32_t o[8] = { mono(a.x), mono(a.y), mono(a.z), mono(a.w),
                      mono(b.x), mono(b.y), mono(b.z), mono(b.w) };

    // ---- value-only network: sort-8 desc + 3-level symmetric merge ----
    uint32_t k[8];
#pragma unroll
    for (int j = 0; j < 8; ++j) k[j] = o[j];

    CE32(k[0],k[1]) CE32(k[2],k[3]) CE32(k[4],k[5]) CE32(k[6],k[7])
    CE32(k[0],k[2]) CE32(k[1],k[3]) CE32(k[4],k[6]) CE32(k[5],k[7])
    CE32(k[1],k[2]) CE32(k[5],k[6])
    CE32(k[0],k[4]) CE32(k[1],k[5]) CE32(k[2],k[6]) CE32(k[3],k[7])
    CE32(k[2],k[4]) CE32(k[3],k[5])
    CE32(k[1],k[2]) CE32(k[3],k[4]) CE32(k[5],k[6])

    merge_u32<DPP_QUAD_XOR1>(k);
    merge_u32<DPP_QUAD_XOR2>(k);
    merge_u32<DPP_HALF_MIRROR>(k);
    // every lane now holds the token's top-8 VALUES sorted desc in k[0..7]

    // ---- rank each original, deliver expert+1 into byte[rank] of acc ----
    const uint32_t m7 = k[7];
    uint64_t acc  = 0;
    uint32_t qcnt = 0;
#pragma unroll
    for (int j = 0; j < 8; ++j) {
        uint32_t oj = o[j];
        uint32_t q  = (oj >= m7) ? 1u : 0u;
        bool     b2 = (k[3] > oj);
        uint32_t p1 = b2 ? k[5] : k[1];
        bool     b1 = (p1 > oj);
        uint32_t p0 = b1 ? (b2 ? k[6] : k[2]) : (b2 ? k[4] : k[0]);
        bool     b0 = (p0 > oj);
        uint32_t sh = (b2 ? 32u : 0u) + (b1 ? 16u : 0u) + (b0 ? 8u : 0u);
        uint32_t payload = q ? (uint32_t)(sub * 8 + j + 1) : 0u;
        acc  |= (uint64_t)payload << sh;
        qcnt += q;
    }
    acc |= dpp64<DPP_QUAD_XOR1>(acc);
    acc |= dpp64<DPP_QUAD_XOR2>(acc);
    acc |= dpp64<DPP_HALF_MIRROR>(acc);
    qcnt += dpp32<DPP_QUAD_XOR1>(qcnt);
    qcnt += dpp32<DPP_QUAD_XOR2>(qcnt);
    qcnt += dpp32<DPP_HALF_MIRROR>(qcnt);

    uint32_t mybyte = (uint32_t)(acc >> (sub * 8)) & 0xFFu;
    uint32_t zf = (mybyte == 0) ? 1u : 0u;
    zf |= dpp32<DPP_QUAD_XOR1>(zf);
    zf |= dpp32<DPP_QUAD_XOR2>(zf);
    zf |= dpp32<DPP_HALF_MIRROR>(zf);

    const bool bad = (qcnt != 8u) || (zf != 0u);   // group-uniform, exact detector

    // flag byte per wave: bit g = bad of token group g
    unsigned long long bm = __ballot(bad);
    if (lane == 0) {
        bm &= 0x0101010101010101ULL;
        unsigned char fb = (unsigned char)((bm * 0x0102040810204080ULL) >> 56);
        flags[(long)blockIdx.x * 4 + wv] = fb;
    }

    // ---- outputs (provisional if bad; fixup overwrites) ----
    uint32_t t4a = (sub & 4) ? k[4] : k[0];
    uint32_t t4b = (sub & 4) ? k[5] : k[1];
    uint32_t t4c = (sub & 4) ? k[6] : k[2];
    uint32_t t4d = (sub & 4) ? k[7] : k[3];
    uint32_t t2a = (sub & 2) ? t4c : t4a;
    uint32_t t2b = (sub & 2) ? t4d : t4b;
    uint32_t selmono = (sub & 1) ? t2b : t2a;
    int idx = (int)mybyte - 1;

    const float v  = unmono(selmono);
    const float mv = unmono(k[0]);

    float e = __expf(v - mv);
    float s = e;
    s += dppf<DPP_QUAD_XOR1>(s);
    s += dppf<DPP_QUAD_XOR2>(s);
    s += dppf<DPP_HALF_MIRROR>(s);
    float wgt = e * __builtin_amdgcn_rcpf(s);

    if (act) {
        const long oi = t0 * 8 + lane;           // == token*8 + sub
        __builtin_nontemporal_store(wgt,        &out_w[oi]);
        __builtin_nontemporal_store((float)idx, &out_id[oi]);
        __builtin_nontemporal_store((float)oi,  &out_tei[oi]);
    }
}

// exact scalar redo of flagged tokens (stable tie-break: lowest expert index)
__global__ __launch_bounds__(256) void topk_fix(
    const float* __restrict__ logits,
    float* __restrict__ out_w,
    float* __restrict__ out_id,
    float* __restrict__ out_tei,
    const unsigned char* __restrict__ flags,
    int NW, int T)
{
    const int i = (int)(blockIdx.x * blockDim.x + threadIdx.x);  // flag byte idx
    if (i >= NW) return;
    const unsigned char fb = flags[i];
    if (!fb) return;

    for (int g = 0; g < 8; ++g) {
        if (!(fb & (1u << g))) continue;
        const long t = (long)i * 8 + g;
        if (t >= T) continue;
        const float* L = logits + t * 64;

        unsigned long long used = 0;
        float sv[8]; int si[8];
        for (int r = 0; r < 8; ++r) {
            float bv = -INFINITY; int bi = 0;
            for (int e = 0; e < 64; ++e) {
                if ((used >> e) & 1ull) continue;
                float x = L[e];
                if (x > bv) { bv = x; bi = e; }   // ascending scan: ties keep lowest e
            }
            used |= 1ull << bi;
            sv[r] = bv; si[r] = bi;
        }
        float m = sv[0], s = 0.f;
        for (int r = 0; r < 8; ++r) s += expf(sv[r] - m);
        for (int r = 0; r < 8; ++r) {
            const long oi = t * 8 + r;
            out_w[oi]   = expf(sv[r] - m) / s;
            out_id[oi]  = (float)si[r];
            out_tei[oi] = (float)oi;
        }
    }
}

// ---------- fallback: R4's exact f64 network (used only if ws too small) ----
#define CED(x, y) { double hi_ = fmax(x, y), lo_ = fmin(x, y); x = hi_; y = lo_; }

template<int CTRL>
static __device__ __forceinline__ double dpp64d(double x) {
    uint64_t b = (uint64_t)__double_as_longlong(x);
    int lo = __builtin_amdgcn_update_dpp(0, (int)(uint32_t)b,         CTRL, 0xF, 0xF, true);
    int hi = __builtin_amdgcn_update_dpp(0, (int)(uint32_t)(b >> 32), CTRL, 0xF, 0xF, true);
    return __longlong_as_double((long long)(((uint64_t)(uint32_t)hi << 32) | (uint32_t)lo));
}
template<int CTRL>
static __device__ __forceinline__ void merge_f64(double k[8]) {
    double m[8];
#pragma unroll
    for (int i = 0; i < 8; ++i) { double p = dpp64d<CTRL>(k[7 - i]); m[i] = fmax(k[i], p); }
    CED(m[0], m[4]) CED(m[1], m[5]) CED(m[2], m[6]) CED(m[3], m[7])
    CED(m[0], m[2]) CED(m[1], m[3]) CED(m[4], m[6]) CED(m[5], m[7])
    CED(m[0], m[1]) CED(m[2], m[3]) CED(m[4], m[5]) CED(m[6], m[7])
#pragma unroll
    for (int i = 0; i < 8; ++i) k[i] = m[i];
}

__global__ __launch_bounds__(256) void topk_exact_f64(
    const float* __restrict__ logits,
    float* __restrict__ out_w,
    float* __restrict__ out_id,
    float* __restrict__ out_tei,
    int T)
{
    const int  lane = threadIdx.x & 63;
    const int  wv   = (int)(threadIdx.x >> 6);
    const long t0   = (long)blockIdx.x * 32 + (long)wv * 8;
    if (t0 >= T) return;
    const int  sub = lane & 7;
    const bool act = (t0 + (lane >> 3)) < T;

    const f32x4* src = reinterpret_cast<const f32x4*>(logits)
                     + (act ? (t0 * 16 + (long)lane * 2) : 0);
    f32x4 a = __builtin_nontemporal_load(src);
    f32x4 b = __builtin_nontemporal_load(src + 1);

    const float vals[8] = {a.x, a.y, a.z, a.w, b.x, b.y, b.z, b.w};
    const double base = (double)(63 - sub * 8) * 0.015625;
    double k[8];
#pragma unroll
    for (int j = 0; j < 8; ++j)
        k[j] = (double)mono(vals[j]) + (base - j * 0.015625);

    CED(k[0],k[1]) CED(k[2],k[3]) CED(k[4],k[5]) CED(k[6],k[7])
    CED(k[0],k[2]) CED(k[1],k[3]) CED(k[4],k[6]) CED(k[5],k[7])
    CED(k[1],k[2]) CED(k[5],k[6])
    CED(k[0],k[4]) CED(k[1],k[5]) CED(k[2],k[6]) CED(k[3],k[7])
    CED(k[2],k[4]) CED(k[3],k[5])
    CED(k[1],k[2]) CED(k[3],k[4]) CED(k[5],k[6])

    merge_f64<DPP_QUAD_XOR1>(k);
    merge_f64<DPP_QUAD_XOR2>(k);
    merge_f64<DPP_HALF_MIRROR>(k);

    double t4a = (sub & 4) ? k[4] : k[0];
    double t4b = (sub & 4) ? k[5] : k[1];
    double t4c = (sub & 4) ? k[6] : k[2];
    double t4d = (sub & 4) ? k[7] : k[3];
    double t2a = (sub & 2) ? t4c : t4a;
    double t2b = (sub & 2) ? t4d : t4b;
    double sel = (sub & 1) ? t2b : t2a;

    float mv = unmono((uint32_t)k[0]);
    uint32_t os   = (uint32_t)sel;
    double   frac = sel - (double)os;
    int      idx  = 63 - (int)(frac * 64.0 + 0.5);
    float    v    = unmono(os);

    float e = __expf(v - mv);
    float s = e;
    s += dppf<DPP_QUAD_XOR1>(s);
    s += dppf<DPP_QUAD_XOR2>(s);
    s += dppf<DPP_HALF_MIRROR>(s);
    float wgt = e * __builtin_amdgcn_rcpf(s);

    if (act) {
        const long oi = t0 * 8 + lane;
        __builtin_nontemporal_store(wgt,        &out_w[oi]);
        __builtin_nontemporal_store((float)idx, &out_id[oi]);
        __builtin_nontemporal_store((float)oi,  &out_tei[oi]);
    }
}

extern "C" void kernel_launch(void* const* d_in, const int* in_sizes, int n_in,
                              void* d_out, int out_size, void* d_ws, size_t ws_size,
                              hipStream_t stream) {
    const float* logits = (const float*)d_in[0];
    const int T = in_sizes[0] / 64;

    float* outw = (float*)d_out;
    float* outi = outw + (size_t)T * 8;
    float* outt = outi + (size_t)T * 8;

    const int NW     = (T + 7) / 8;          // waves = flag bytes
    const int blocks = (T + 31) / 32;        // 32 tokens per 256-thread block

    if (ws_size >= (size_t)NW) {
        unsigned char* flags = (unsigned char*)d_ws;
        hipLaunchKernelGGL(topk_fast, dim3(blocks), dim3(256), 0, stream,
                           logits, outw, outi, outt, flags, T);
        hipLaunchKernelGGL(topk_fix, dim3((NW + 255) / 256), dim3(256), 0, stream,
                           logits, outw, outi, outt, flags, NW, T);
    } else {
        hipLaunchKernelGGL(topk_exact_f64, dim3(blocks), dim3(256), 0, stream,
                           logits, outw, outi, outt, T);
    }
}

// Round 9
// 70.055 us; speedup vs baseline: 1.8536x; 1.8536x over previous
//
#include <hip/hip_runtime.h>
#include <stdint.h>

// Fused softmax + top-8 (renormalized) over 64 experts.
// 1 wave = 8 tokens; 8 lanes/token; 8 logits/lane. Single kernel.
// Fast path (vcc-free): u32 value network (v_max_u32/v_min_u32) ->
//   every lane holds the token's top-8 values sorted desc; own-slot value via
//   v_bfi select tree; index = lowest expert id matching that value, via
//   arithmetic match-mask + v_min_u32 group reduce (no vcc anywhere).
// Exact-tie handling: min-matching-id is wrong ONLY if two EQUAL values both
//   sit inside the top-8 (adjacent slots k[i]==k[i+1]). Detected exactly with
//   7 equality masks; rare waves take a wave-uniform in-kernel u64-key serial
//   extraction (exact jax.lax.top_k stable tie-break: lower index first).

typedef float f32x4 __attribute__((ext_vector_type(4)));

#define DPP_QUAD_XOR1   0xB1   // quad_perm(1,0,3,2)  : lane ^ 1
#define DPP_QUAD_XOR2   0x4E   // quad_perm(2,3,0,1)  : lane ^ 2
#define DPP_HALF_MIRROR 0x141  // row_half_mirror     : lane <-> 7-lane (in 8)

template<int CTRL>
static __device__ __forceinline__ uint32_t dpp32(uint32_t x) {
    return (uint32_t)__builtin_amdgcn_update_dpp(0, (int)x, CTRL, 0xF, 0xF, true);
}
template<int CTRL>
static __device__ __forceinline__ uint64_t dpp64(uint64_t x) {
    int lo = __builtin_amdgcn_update_dpp(0, (int)(uint32_t)x,         CTRL, 0xF, 0xF, true);
    int hi = __builtin_amdgcn_update_dpp(0, (int)(uint32_t)(x >> 32), CTRL, 0xF, 0xF, true);
    return ((uint64_t)(uint32_t)hi << 32) | (uint32_t)lo;
}
template<int CTRL>
static __device__ __forceinline__ float dppf(float x) {
    int i = __builtin_amdgcn_update_dpp(0, __float_as_int(x), CTRL, 0xF, 0xF, true);
    return __int_as_float(i);
}

// vcc-free compare-exchange desc on u32 (v_max_u32 + v_min_u32)
#define CE32(x, y) { uint32_t gt_ = (x > y) ? x : y; uint32_t lt_ = (x > y) ? y : x; \
                     x = gt_; y = lt_; }
// u64 CE (rare fallback only; vcc ok there)
#define CEU(x, y) { uint64_t a_ = x, b_ = y; bool c_ = a_ < b_; \
                    x = c_ ? b_ : a_; y = c_ ? a_ : b_; }

template<int CTRL>
static __device__ __forceinline__ void merge_u32(uint32_t k[8]) {
    uint32_t m[8];
#pragma unroll
    for (int i = 0; i < 8; ++i) {
        uint32_t p = dpp32<CTRL>(k[7 - i]);
        m[i] = (k[i] > p) ? k[i] : p;      // v_max_u32
    }
    CE32(m[0], m[4]) CE32(m[1], m[5]) CE32(m[2], m[6]) CE32(m[3], m[7])
    CE32(m[0], m[2]) CE32(m[1], m[3]) CE32(m[4], m[6]) CE32(m[5], m[7])
    CE32(m[0], m[1]) CE32(m[2], m[3]) CE32(m[4], m[5]) CE32(m[6], m[7])
#pragma unroll
    for (int i = 0; i < 8; ++i) k[i] = m[i];
}

static __device__ __forceinline__ uint32_t mono(float v) {
    uint32_t u = __float_as_uint(v);
    return u ^ (uint32_t)(((int32_t)u >> 31) | 0x80000000);   // ascending map
}
static __device__ __forceinline__ float unmono(uint32_t m) {
    uint32_t u = (m & 0x80000000u) ? (m ^ 0x80000000u) : ~m;
    return __uint_as_float(u);
}
// 0xFFFFFFFF if d != 0, else 0  (vcc-free nonzero test)
static __device__ __forceinline__ uint32_t nzmask(uint32_t d) {
    return (uint32_t)(((int32_t)(d | (0u - d))) >> 31);
}
// mask ? b : a  -> v_bfi_b32
static __device__ __forceinline__ uint32_t bsel(uint32_t mask, uint32_t b, uint32_t a) {
    return (mask & b) | (~mask & a);
}

__global__ __launch_bounds__(256, 8) void topk_softmax_k(
    const float* __restrict__ logits,
    float* __restrict__ out_w,
    float* __restrict__ out_id,
    float* __restrict__ out_tei,
    int T)
{
    const int  lane = threadIdx.x & 63;
    const int  wv   = (int)(threadIdx.x >> 6);
    const long t0   = (long)blockIdx.x * 32 + (long)wv * 8;   // first token of wave
    if (t0 >= T) return;

    const int  sub = lane & 7;
    const bool act = (t0 + (lane >> 3)) < T;

    // lane l reads logits[t0*64 + l*8 .. +7] -> wave covers 2KiB contiguous
    const f32x4* src = reinterpret_cast<const f32x4*>(logits)
                     + (act ? (t0 * 16 + (long)lane * 2) : 0);
    f32x4 a = __builtin_nontemporal_load(src);
    f32x4 b = __builtin_nontemporal_load(src + 1);

    // originals (ascending-mapped); expert id of o[j] is sub*8 + j
    uint32_t o[8] = { mono(a.x), mono(a.y), mono(a.z), mono(a.w),
                      mono(b.x), mono(b.y), mono(b.z), mono(b.w) };

    // ---- value-only network: sort-8 desc + 3-level symmetric merge ----
    uint32_t k[8];
#pragma unroll
    for (int j = 0; j < 8; ++j) k[j] = o[j];

    CE32(k[0],k[1]) CE32(k[2],k[3]) CE32(k[4],k[5]) CE32(k[6],k[7])
    CE32(k[0],k[2]) CE32(k[1],k[3]) CE32(k[4],k[6]) CE32(k[5],k[7])
    CE32(k[1],k[2]) CE32(k[5],k[6])
    CE32(k[0],k[4]) CE32(k[1],k[5]) CE32(k[2],k[6]) CE32(k[3],k[7])
    CE32(k[2],k[4]) CE32(k[3],k[5])
    CE32(k[1],k[2]) CE32(k[3],k[4]) CE32(k[5],k[6])

    merge_u32<DPP_QUAD_XOR1>(k);
    merge_u32<DPP_QUAD_XOR2>(k);
    merge_u32<DPP_HALF_MIRROR>(k);
    // every lane now holds the token's top-8 VALUES sorted desc (group-uniform)

    // ---- exact duplicate-in-top8 detector (vcc-free masks) ----
    uint32_t goodm = 0xFFFFFFFFu;
#pragma unroll
    for (int i = 0; i < 7; ++i) goodm &= nzmask(k[i] ^ k[i + 1]);

    // ---- own-slot value via bfi select tree (vcc-free) ----
    const uint32_t m1 = 0u - (uint32_t)(sub & 1);
    const uint32_t m2 = 0u - (uint32_t)((sub >> 1) & 1);
    const uint32_t m4 = 0u - (uint32_t)((sub >> 2) & 1);
    uint32_t t4a = bsel(m4, k[4], k[0]);
    uint32_t t4b = bsel(m4, k[5], k[1]);
    uint32_t t4c = bsel(m4, k[6], k[2]);
    uint32_t t4d = bsel(m4, k[7], k[3]);
    uint32_t t2a = bsel(m2, t4c, t4a);
    uint32_t t2b = bsel(m2, t4d, t4b);
    uint32_t selmono = bsel(m1, t2b, t2a);
    uint32_t maxmono = k[0];

    // ---- index = lowest expert id with value == selmono (vcc-free) ----
    const uint32_t idbase = (uint32_t)(sub * 8);
    uint32_t loc = 0xFFFFFFFFu;
#pragma unroll
    for (int j = 0; j < 8; ++j) {
        uint32_t cand = (idbase + (uint32_t)j) | nzmask(o[j] ^ selmono);
        loc = (loc < cand) ? loc : cand;            // v_min_u32
    }
    { uint32_t p = dpp32<DPP_QUAD_XOR1>(loc);   loc = (loc < p) ? loc : p; }
    { uint32_t p = dpp32<DPP_QUAD_XOR2>(loc);   loc = (loc < p) ? loc : p; }
    { uint32_t p = dpp32<DPP_HALF_MIRROR>(loc); loc = (loc < p) ? loc : p; }
    int idx = (int)loc;

    // ---- rare exact redo (wave-uniform branch; vcc fine here) ----
    if (__any(goodm != 0xFFFFFFFFu)) {
        const uint32_t cb = (uint32_t)(63 - sub * 8);
        uint64_t kk[8];
#pragma unroll
        for (int j = 0; j < 8; ++j)
            kk[j] = ((uint64_t)o[j] << 6) | (uint64_t)(cb - (uint32_t)j);

        CEU(kk[0],kk[1]) CEU(kk[2],kk[3]) CEU(kk[4],kk[5]) CEU(kk[6],kk[7])
        CEU(kk[0],kk[2]) CEU(kk[1],kk[3]) CEU(kk[4],kk[6]) CEU(kk[5],kk[7])
        CEU(kk[1],kk[2]) CEU(kk[5],kk[6])
        CEU(kk[0],kk[4]) CEU(kk[1],kk[5]) CEU(kk[2],kk[6]) CEU(kk[3],kk[7])
        CEU(kk[2],kk[4]) CEU(kk[3],kk[5])
        CEU(kk[1],kk[2]) CEU(kk[3],kk[4]) CEU(kk[5],kk[6])

        uint64_t mykey = 0, mtop = 0;
#pragma unroll
        for (int r = 0; r < 8; ++r) {
            uint64_t w = kk[0];
            { uint64_t t = dpp64<DPP_QUAD_XOR1>(w);   if (t > w) w = t; }
            { uint64_t t = dpp64<DPP_QUAD_XOR2>(w);   if (t > w) w = t; }
            { uint64_t t = dpp64<DPP_HALF_MIRROR>(w); if (t > w) w = t; }
            if (r == 0)   mtop  = w;
            if (sub == r) mykey = w;
            bool pop = (kk[0] == w);   // unique keys -> one lane per group pops
            kk[0] = pop ? kk[1] : kk[0];
            kk[1] = pop ? kk[2] : kk[1];
            kk[2] = pop ? kk[3] : kk[2];
            kk[3] = pop ? kk[4] : kk[3];
            kk[4] = pop ? kk[5] : kk[4];
            kk[5] = pop ? kk[6] : kk[5];
            kk[6] = pop ? kk[7] : kk[6];
            kk[7] = pop ? 0     : kk[7];
        }
        selmono = (uint32_t)(mykey >> 6);
        maxmono = (uint32_t)(mtop  >> 6);
        idx = 63 - (int)((uint32_t)mykey & 63u);
    }

    // ---- renormalized softmax over the selected 8 ----
    const float v  = unmono(selmono);
    const float mv = unmono(maxmono);
    float e = __expf(v - mv);
    float s = e;
    s += dppf<DPP_QUAD_XOR1>(s);
    s += dppf<DPP_QUAD_XOR2>(s);
    s += dppf<DPP_HALF_MIRROR>(s);
    float wgt = e * __builtin_amdgcn_rcpf(s);

    if (act) {
        const long oi = t0 * 8 + lane;           // == token*8 + sub
        __builtin_nontemporal_store(wgt,        &out_w[oi]);
        __builtin_nontemporal_store((float)idx, &out_id[oi]);
        __builtin_nontemporal_store((float)oi,  &out_tei[oi]);
    }
}

extern "C" void kernel_launch(void* const* d_in, const int* in_sizes, int n_in,
                              void* d_out, int out_size, void* d_ws, size_t ws_size,
                              hipStream_t stream) {
    const float* logits = (const float*)d_in[0];
    const int T = in_sizes[0] / 64;

    float* outw = (float*)d_out;
    float* outi = outw + (size_t)T * 8;
    float* outt = outi + (size_t)T * 8;

    const int blocks = (T + 31) / 32;   // 32 tokens per 256-thread block
    hipLaunchKernelGGL(topk_softmax_k, dim3(blocks), dim3(256), 0, stream,
                       logits, outw, outi, outt, T);
}